// Round 4
// baseline (460.625 us; speedup 1.0000x reference)
//
#include <hip/hip_runtime.h>
#include <hip/hip_bf16.h>
#include <stdint.h>

#define B_  4
#define T_  300
#define U_  60
#define H_  1024
#define V_  1000
#define M_TOT (B_*T_*U_)   // 72000
#define KDIM 1024
#define WK  1056           // padded W row stride (shorts): 2112B = 33*64B
#define PK  1040           // padded proj row stride (floats): 4160B = 65*64B

typedef __attribute__((ext_vector_type(8))) short short8;
typedef __attribute__((ext_vector_type(4))) float f32x4;
typedef __attribute__((ext_vector_type(4))) int int4v;

__device__ __forceinline__ short f2bf(float f) {
    union { float f; uint32_t u; } c; c.f = f;
    uint32_t u = c.u;
    uint32_t r = (u + 0x7FFFu + ((u >> 16) & 1u)) >> 16;
    return (short)r;
}

__device__ __forceinline__ float fast_tanh(float x) {
    float e = __expf(2.0f * x);
    float r = __builtin_amdgcn_rcpf(e + 1.0f);
    return 1.0f - 2.0f * r;
}

// in: fp32 [R][C] row-major -> out: bf16 [C rows][R cols] with row stride ostride
__global__ void transpose_cvt(const float* __restrict__ in, short* __restrict__ out,
                              int R, int C, int ostride) {
    __shared__ float tile[64][65];
    const int tx = threadIdx.x & 63, ty = threadIdx.x >> 6;
    const int r0 = blockIdx.y * 64, c0 = blockIdx.x * 64;
#pragma unroll
    for (int i = 0; i < 16; ++i) {
        int r = r0 + i * 4 + ty, c = c0 + tx;
        float v = 0.f;
        if (r < R && c < C) v = in[(long)r * C + c];
        tile[i * 4 + ty][tx] = v;
    }
    __syncthreads();
#pragma unroll
    for (int i = 0; i < 16; ++i) {
        int oc = c0 + i * 4 + ty;
        int orr = r0 + tx;
        out[(long)oc * ostride + orr] = f2bf(tile[tx][i * 4 + ty]);
    }
}

// P[M][PK] = bf16(X[M][512]) @ Wt[k_off:k_off+512]^T (+ b1)
__global__ __launch_bounds__(256, 2) void proj_gemm(
        const float* __restrict__ X, int M, int k_off,
        const short* __restrict__ Wt,   // [1024 h][WK] bf16
        const float* __restrict__ b1,
        float* __restrict__ P)
{
    __shared__ short As[64 * 64];
    const int tid = threadIdx.x;
    const int lane = tid & 63;
    const int w = tid >> 6;
    const int wm = w >> 1, wn = w & 1;
    const int m0 = blockIdx.x * 64, n0 = blockIdx.y * 64;

    f32x4 acc[2][2] = {};
    for (int k0 = 0; k0 < 512; k0 += 64) {
#pragma unroll
        for (int c = 0; c < 2; ++c) {
            int lin = tid + 256 * c;
            int row = lin >> 3, k8 = lin & 7;
            int m = m0 + row;
            short vals[8];
            if (m < M) {
                const float* xp = X + (long)m * 512 + k0 + k8 * 8;
#pragma unroll
                for (int j = 0; j < 8; ++j) vals[j] = f2bf(xp[j]);
            } else {
#pragma unroll
                for (int j = 0; j < 8; ++j) vals[j] = 0;
            }
            int byte = row * 128 + k8 * 16;
            byte ^= (row & 7) << 4;
            *(int4v*)((char*)As + byte) = *(const int4v*)vals;
        }
        __syncthreads();
#pragma unroll
        for (int ks = 0; ks < 2; ++ks) {
            short8 af[2];
#pragma unroll
            for (int mf = 0; mf < 2; ++mf) {
                int row = wm * 32 + mf * 16 + (lane & 15);
                int byte = row * 128 + ks * 64 + (lane >> 4) * 16;
                byte ^= (row & 7) << 4;
                af[mf] = *(const short8*)((char*)As + byte);
            }
#pragma unroll
            for (int nf = 0; nf < 2; ++nf) {
                int h = n0 + wn * 32 + nf * 16 + (lane & 15);
                const short* bp = Wt + (long)h * WK + k_off + k0 + ks * 32 + (lane >> 4) * 8;
                short8 bfv = *(const short8*)bp;
#pragma unroll
                for (int mf = 0; mf < 2; ++mf)
                    acc[mf][nf] = __builtin_amdgcn_mfma_f32_16x16x32_bf16(af[mf], bfv, acc[mf][nf], 0, 0, 0);
            }
        }
        __syncthreads();
    }
#pragma unroll
    for (int mf = 0; mf < 2; ++mf)
#pragma unroll
        for (int nf = 0; nf < 2; ++nf) {
            int h = n0 + wn * 32 + nf * 16 + (lane & 15);
            float bb = b1 ? b1[h] : 0.f;
#pragma unroll
            for (int j = 0; j < 4; ++j) {
                int m = m0 + wm * 32 + mf * 16 + (lane >> 4) * 4 + j;
                if (m < M) P[(long)m * PK + h] = acc[mf][nf][j] + bb;
            }
        }
}

__device__ __forceinline__ void gen_slice(char* dst_byte,
        f32x4 e0, f32x4 e1, f32x4 d0, f32x4 d1) {
    short vals[8];
#pragma unroll
    for (int j = 0; j < 4; ++j) vals[j]     = f2bf(fast_tanh(e0[j] + d0[j]));
#pragma unroll
    for (int j = 0; j < 4; ++j) vals[4 + j] = f2bf(fast_tanh(e1[j] + d1[j]));
    *(int4v*)dst_byte = *(const int4v*)vals;
}

// out[m][v] = tanh(encP[bt] + decP[bu]) @ W2t^T + b2, A generated on the fly.
// Block 64m x 256n, 8 waves (2m x 4n), wave tile 32x64 -> acc = 32 AGPR.
// Total regs <= 128/wave so TWO blocks fit per CU (the R2/R3 regression was
// VGPR+AGPR > 128 -> 1 block/CU -> latency-bound at 8 waves).
__global__ __launch_bounds__(512, 4) void joint_gemm(
        const float* __restrict__ encP,  // [1200][PK] fp32
        const float* __restrict__ decP,  // [240][PK] fp32 (b1 pre-added)
        const short* __restrict__ W2t,   // [1024 n][WK] bf16
        const float* __restrict__ b2,
        float* __restrict__ out)
{
    __shared__ short As[2][64 * 64];     // double-buffered A slice, XOR-swizzled
    const int tid = threadIdx.x;
    const int lane = tid & 63;
    const int w = tid >> 6;
    const int wm = w >> 2;               // 0..1  (m sub-tile)
    const int wn = w & 3;                // 0..3  (n sub-tile)
    const int m0 = blockIdx.x * 64;
    const int n0 = blockIdx.y * 256;

    // per-thread A-row assignment (8 k-floats per 64-wide slice)
    const int arow = tid >> 3;
    const int k8 = tid & 7;
    const int am = m0 + arow;
    const int bt = am / U_;
    const int u = am - bt * U_;
    const int bidx = am / (T_ * U_);
    const float* eptr = encP + (long)bt * PK + k8 * 8;
    const float* dptr = decP + (long)(bidx * U_ + u) * PK + k8 * 8;
    const int wbyte = (arow * 128 + k8 * 16) ^ ((arow & 7) << 4);

    f32x4 acc[2][4] = {};
    const short* bbase[4];
#pragma unroll
    for (int nf = 0; nf < 4; ++nf) {
        int n = n0 + wn * 64 + nf * 16 + (lane & 15);
        bbase[nf] = W2t + (long)n * WK + (lane >> 4) * 8;
    }

    // prologue: gen slice 0, prefetch e/d for slice 1
    f32x4 e0 = *(const f32x4*)(eptr);
    f32x4 e1 = *(const f32x4*)(eptr + 4);
    f32x4 d0 = *(const f32x4*)(dptr);
    f32x4 d1 = *(const f32x4*)(dptr + 4);
    gen_slice((char*)&As[0][0] + wbyte, e0, e1, d0, d1);
    e0 = *(const f32x4*)(eptr + 64);
    e1 = *(const f32x4*)(eptr + 68);
    d0 = *(const f32x4*)(dptr + 64);
    d1 = *(const f32x4*)(dptr + 68);
    asm volatile("s_waitcnt lgkmcnt(0)" ::: "memory");
    __builtin_amdgcn_s_barrier();

#pragma unroll 2
    for (int t = 0; t < 16; ++t) {
        const int k0 = t * 64;
        // 1) issue B loads for THIS iteration first (longest latency)
        short8 bfr[2][4];
#pragma unroll
        for (int ks = 0; ks < 2; ++ks)
#pragma unroll
            for (int nf = 0; nf < 4; ++nf)
                bfr[ks][nf] = *(const short8*)(bbase[nf] + k0 + ks * 32);
        // 2) generate next A slice (VALU covers B latency)
        if (t < 15) {
            gen_slice((char*)&As[(t & 1) ^ 1][0] + wbyte, e0, e1, d0, d1);
            if (t < 14) {
                e0 = *(const f32x4*)(eptr + k0 + 128);
                e1 = *(const f32x4*)(eptr + k0 + 132);
                d0 = *(const f32x4*)(dptr + k0 + 128);
                d1 = *(const f32x4*)(dptr + k0 + 132);
            }
        }
        // 3) A fragments from LDS + MFMA
        const char* rb = (const char*)&As[t & 1][0];
#pragma unroll
        for (int ks = 0; ks < 2; ++ks) {
            short8 af[2];
#pragma unroll
            for (int mf = 0; mf < 2; ++mf) {
                int row = wm * 32 + mf * 16 + (lane & 15);
                int byte = (row * 128 + ks * 64 + (lane >> 4) * 16) ^ ((row & 7) << 4);
                af[mf] = *(const short8*)(rb + byte);
            }
#pragma unroll
            for (int nf = 0; nf < 4; ++nf)
#pragma unroll
                for (int mf = 0; mf < 2; ++mf)
                    acc[mf][nf] = __builtin_amdgcn_mfma_f32_16x16x32_bf16(
                        af[mf], bfr[ks][nf], acc[mf][nf], 0, 0, 0);
        }
        // 4) LDS-only barrier: global loads stay in flight
        if (t < 15) {
            asm volatile("s_waitcnt lgkmcnt(0)" ::: "memory");
            __builtin_amdgcn_s_barrier();
        }
    }

    // epilogue: + b2, store fp32
#pragma unroll
    for (int nf = 0; nf < 4; ++nf) {
        int n = n0 + wn * 64 + nf * 16 + (lane & 15);
        float bv = (n < V_) ? b2[n] : 0.f;
#pragma unroll
        for (int mf = 0; mf < 2; ++mf) {
#pragma unroll
            for (int j = 0; j < 4; ++j) {
                int m = m0 + wm * 32 + mf * 16 + (lane >> 4) * 4 + j;
                if (n < V_)
                    out[(long)m * V_ + n] = acc[mf][nf][j] + bv;
            }
        }
    }
}

extern "C" void kernel_launch(void* const* d_in, const int* in_sizes, int n_in,
                              void* d_out, int out_size, void* d_ws, size_t ws_size,
                              hipStream_t stream) {
    const float* enc = (const float*)d_in[0];
    const float* dec = (const float*)d_in[1];
    const float* W1  = (const float*)d_in[2];
    const float* b1  = (const float*)d_in[3];
    const float* W2  = (const float*)d_in[4];
    const float* b2  = (const float*)d_in[5];
    float* out = (float*)d_out;

    char* ws = (char*)d_ws;
    size_t off = 0;
    short* W1t  = (short*)(ws + off); off += (size_t)1024 * WK * 2;
    short* W2t  = (short*)(ws + off); off += (size_t)1024 * WK * 2;
    float* encP = (float*)(ws + off); off += (size_t)1200 * PK * 4;
    float* decP = (float*)(ws + off);

    transpose_cvt<<<dim3(16, 16), 256, 0, stream>>>(W1, W1t, 1024, 1024, WK);
    transpose_cvt<<<dim3(16, 16), 256, 0, stream>>>(W2, W2t, 1024, 1000, WK);

    proj_gemm<<<dim3(19, 16), 256, 0, stream>>>(enc, 1200, 0,   W1t, nullptr, encP);
    proj_gemm<<<dim3(4, 16),  256, 0, stream>>>(dec, 240,  512, W1t, b1,      decP);

    joint_gemm<<<dim3(1125, 4), 512, 0, stream>>>(encP, decP, W2t, b2, out);
}

// Round 5
// 386.375 us; speedup vs baseline: 1.1922x; 1.1922x over previous
//
#include <hip/hip_runtime.h>
#include <hip/hip_bf16.h>
#include <stdint.h>

#define B_  4
#define T_  300
#define U_  60
#define V_  1000
#define M_TOT (B_*T_*U_)   // 72000
#define WK  1056           // padded W row stride (shorts)
#define PK  1040           // padded proj row stride (floats)

#define BM 128
#define BN 256
#define BK 32
#define KSTEPS 32          // 1024 / BK

typedef __attribute__((ext_vector_type(8))) short short8;
typedef __attribute__((ext_vector_type(4))) float f32x4;
typedef __attribute__((ext_vector_type(4))) int int4v;

__device__ __forceinline__ short f2bf(float f) {
    union { float f; uint32_t u; } c; c.f = f;
    uint32_t u = c.u;
    uint32_t r = (u + 0x7FFFu + ((u >> 16) & 1u)) >> 16;
    return (short)r;
}

__device__ __forceinline__ float fast_tanh(float x) {
    float e = __expf(2.0f * x);
    float r = __builtin_amdgcn_rcpf(e + 1.0f);
    return 1.0f - 2.0f * r;
}

__device__ __forceinline__ int swz(int r) { return (r & 3) ^ ((r >> 2) & 3); }

__device__ __forceinline__ void gl_lds16(const void* g, void* l) {
    __builtin_amdgcn_global_load_lds(
        (const __attribute__((address_space(1))) void*)g,
        (__attribute__((address_space(3))) void*)l, 16, 0, 0);
}

// in: fp32 [R][C] row-major -> out: bf16 [C rows][R cols], row stride ostride
__global__ void transpose_cvt(const float* __restrict__ in, short* __restrict__ out,
                              int R, int C, int ostride) {
    __shared__ float tile[64][65];
    const int tx = threadIdx.x & 63, ty = threadIdx.x >> 6;
    const int r0 = blockIdx.y * 64, c0 = blockIdx.x * 64;
#pragma unroll
    for (int i = 0; i < 16; ++i) {
        int r = r0 + i * 4 + ty, c = c0 + tx;
        float v = 0.f;
        if (r < R && c < C) v = in[(long)r * C + c];
        tile[i * 4 + ty][tx] = v;
    }
    __syncthreads();
#pragma unroll
    for (int i = 0; i < 16; ++i) {
        int oc = c0 + i * 4 + ty;
        int orr = r0 + tx;
        out[(long)oc * ostride + orr] = f2bf(tile[tx][i * 4 + ty]);
    }
}

// P[M][PK] = bf16(X[M][512]) @ Wt[k_off:k_off+512]^T (+ b1)
__global__ __launch_bounds__(256, 2) void proj_gemm(
        const float* __restrict__ X, int M, int k_off,
        const short* __restrict__ Wt,
        const float* __restrict__ b1,
        float* __restrict__ P)
{
    __shared__ short As[64 * 64];
    const int tid = threadIdx.x;
    const int lane = tid & 63;
    const int w = tid >> 6;
    const int wm = w >> 1, wn = w & 1;
    const int m0 = blockIdx.x * 64, n0 = blockIdx.y * 64;

    f32x4 acc[2][2] = {};
    for (int k0 = 0; k0 < 512; k0 += 64) {
#pragma unroll
        for (int c = 0; c < 2; ++c) {
            int lin = tid + 256 * c;
            int row = lin >> 3, k8 = lin & 7;
            int m = m0 + row;
            short vals[8];
            if (m < M) {
                const float* xp = X + (long)m * 512 + k0 + k8 * 8;
#pragma unroll
                for (int j = 0; j < 8; ++j) vals[j] = f2bf(xp[j]);
            } else {
#pragma unroll
                for (int j = 0; j < 8; ++j) vals[j] = 0;
            }
            int byte = row * 128 + k8 * 16;
            byte ^= (row & 7) << 4;
            *(int4v*)((char*)As + byte) = *(const int4v*)vals;
        }
        __syncthreads();
#pragma unroll
        for (int ks = 0; ks < 2; ++ks) {
            short8 af[2];
#pragma unroll
            for (int mf = 0; mf < 2; ++mf) {
                int row = wm * 32 + mf * 16 + (lane & 15);
                int byte = row * 128 + ks * 64 + (lane >> 4) * 16;
                byte ^= (row & 7) << 4;
                af[mf] = *(const short8*)((char*)As + byte);
            }
#pragma unroll
            for (int nf = 0; nf < 2; ++nf) {
                int h = n0 + wn * 32 + nf * 16 + (lane & 15);
                const short* bp = Wt + (long)h * WK + k_off + k0 + ks * 32 + (lane >> 4) * 8;
                short8 bfv = *(const short8*)bp;
#pragma unroll
                for (int mf = 0; mf < 2; ++mf)
                    acc[mf][nf] = __builtin_amdgcn_mfma_f32_16x16x32_bf16(af[mf], bfv, acc[mf][nf], 0, 0, 0);
            }
        }
        __syncthreads();
    }
#pragma unroll
    for (int mf = 0; mf < 2; ++mf)
#pragma unroll
        for (int nf = 0; nf < 2; ++nf) {
            int h = n0 + wn * 32 + nf * 16 + (lane & 15);
            float bb = b1 ? b1[h] : 0.f;
#pragma unroll
            for (int j = 0; j < 4; ++j) {
                int m = m0 + wm * 32 + mf * 16 + (lane >> 4) * 4 + j;
                if (m < M) P[(long)m * PK + h] = acc[mf][nf][j] + bb;
            }
        }
}

// out[m][v] = tanh(encP + decP) @ W2t^T + b2.
// BM=128, BN=256, BK=32. 4 waves (2m x 2n), wave tile 64x128, acc=128 AGPR.
// B staged via global_load_lds with pre-swizzled per-lane source; A generated
// (tanh) into swizzled LDS. One barrier per K-step; loads issued at top of
// iteration, drained at bottom (whole MFMA block in between covers latency).
// 48KB LDS + <=256 regs -> 2 blocks/CU co-resident.
__global__ __launch_bounds__(256, 2) void joint_gemm(
        const float* __restrict__ encP,  // [1200][PK] fp32
        const float* __restrict__ decP,  // [240][PK] fp32 (b1 pre-added)
        const short* __restrict__ W2t,   // [1024 n][WK] bf16 (rows >=1000 zero)
        const float* __restrict__ b2,
        float* __restrict__ out)
{
    __shared__ short As[2][BM * BK];   // 8KB each, swizzled
    __shared__ short Bs[2][BN * BK];   // 16KB each, swizzled

    const int tid = threadIdx.x;
    const int lane = tid & 63;
    const int w = tid >> 6;            // 0..3
    const int wm = w >> 1, wn = w & 1;
    const int ksel = lane >> 4;        // 0..3 k-granule
    const int l15 = lane & 15;
    const int m0 = blockIdx.x * BM;
    const int n0 = blockIdx.y * BN;

    // ---- A-gen assignment: thread -> (row, k-half of 16 elems) ----
    const int arow = tid >> 1;         // 0..127
    const int ah = tid & 1;
    int am = m0 + arow;
    if (am >= M_TOT) am = M_TOT - 1;   // clamp tail (garbage rows masked at store)
    const int bt = am / U_;
    const int u = am - bt * U_;
    const int bidx = am / (T_ * U_);
    const float* eb = encP + (long)bt * PK + ah * 16;
    const float* db = decP + (long)(bidx * U_ + u) * PK + ah * 16;
    const int awb0 = arow * 64 + (((2 * ah)     ^ swz(arow)) << 4);
    const int awb1 = arow * 64 + (((2 * ah + 1) ^ swz(arow)) << 4);

    // ---- B staging source (pre-swizzled so linear LDS dest = swizzled layout) ----
    const short* bsrc[4];
    int bslab[4];
#pragma unroll
    for (int c = 0; c < 4; ++c) {
        int slab = c * 4 + w;                    // wave-uniform
        int r = slab * 16 + (lane >> 2);
        int g = (lane & 3) ^ swz(r);
        bsrc[c] = W2t + (long)(n0 + r) * WK + g * 8;
        bslab[c] = slab * 512;                   // shorts (1KB per slab)
    }

    f32x4 acc[4][8] = {};

    // ---- prologue: stage B(0), gen A(0) ----
#pragma unroll
    for (int c = 0; c < 4; ++c)
        gl_lds16(bsrc[c], (short*)&Bs[0][0] + bslab[c]);
    {
        f32x4 e0 = *(const f32x4*)(eb),      e1 = *(const f32x4*)(eb + 4);
        f32x4 e2 = *(const f32x4*)(eb + 8),  e3 = *(const f32x4*)(eb + 12);
        f32x4 d0 = *(const f32x4*)(db),      d1 = *(const f32x4*)(db + 4);
        f32x4 d2 = *(const f32x4*)(db + 8),  d3 = *(const f32x4*)(db + 12);
        short v[16];
#pragma unroll
        for (int j = 0; j < 4; ++j) v[j]      = f2bf(fast_tanh(e0[j] + d0[j]));
#pragma unroll
        for (int j = 0; j < 4; ++j) v[4 + j]  = f2bf(fast_tanh(e1[j] + d1[j]));
#pragma unroll
        for (int j = 0; j < 4; ++j) v[8 + j]  = f2bf(fast_tanh(e2[j] + d2[j]));
#pragma unroll
        for (int j = 0; j < 4; ++j) v[12 + j] = f2bf(fast_tanh(e3[j] + d3[j]));
        *(int4v*)((char*)&As[0][0] + awb0) = *(const int4v*)&v[0];
        *(int4v*)((char*)&As[0][0] + awb1) = *(const int4v*)&v[8];
    }
    asm volatile("s_waitcnt vmcnt(0) lgkmcnt(0)" ::: "memory");
    __builtin_amdgcn_s_barrier();

#pragma unroll 2
    for (int t = 0; t < KSTEPS; ++t) {
        const int cur = t & 1, nxt = cur ^ 1;
        const int k0n = (t + 1) * BK;
        const bool more = (t + 1 < KSTEPS);

        // 1) issue B(t+1) global_load_lds (in flight across the MFMA block)
        if (more) {
#pragma unroll
            for (int c = 0; c < 4; ++c)
                gl_lds16(bsrc[c] + k0n, (short*)&Bs[nxt][0] + bslab[c]);
        }
        // 2) issue e/d loads for A(t+1)
        f32x4 e0, e1, e2, e3, d0, d1, d2, d3;
        if (more) {
            e0 = *(const f32x4*)(eb + k0n);      e1 = *(const f32x4*)(eb + k0n + 4);
            e2 = *(const f32x4*)(eb + k0n + 8);  e3 = *(const f32x4*)(eb + k0n + 12);
            d0 = *(const f32x4*)(db + k0n);      d1 = *(const f32x4*)(db + k0n + 4);
            d2 = *(const f32x4*)(db + k0n + 8);  d3 = *(const f32x4*)(db + k0n + 12);
        }
        // 3) fragments + MFMA (covers the load latency)
        short8 af[4];
#pragma unroll
        for (int mf = 0; mf < 4; ++mf) {
            int row = wm * 64 + mf * 16 + l15;
            int byte = row * 64 + ((ksel ^ swz(row)) << 4);
            af[mf] = *(const short8*)((const char*)&As[cur][0] + byte);
        }
#pragma unroll
        for (int nh = 0; nh < 2; ++nh) {
            short8 bf[4];
#pragma unroll
            for (int nf2 = 0; nf2 < 4; ++nf2) {
                int row = wn * 128 + (nh * 4 + nf2) * 16 + l15;
                int byte = row * 64 + ((ksel ^ swz(row)) << 4);
                bf[nf2] = *(const short8*)((const char*)&Bs[cur][0] + byte);
            }
#pragma unroll
            for (int nf2 = 0; nf2 < 4; ++nf2)
#pragma unroll
                for (int mf = 0; mf < 4; ++mf)
                    acc[mf][nh * 4 + nf2] = __builtin_amdgcn_mfma_f32_16x16x32_bf16(
                        af[mf], bf[nf2], acc[mf][nh * 4 + nf2], 0, 0, 0);
        }
        // 4) generate A(t+1) into the other buffer
        if (more) {
            short v[16];
#pragma unroll
            for (int j = 0; j < 4; ++j) v[j]      = f2bf(fast_tanh(e0[j] + d0[j]));
#pragma unroll
            for (int j = 0; j < 4; ++j) v[4 + j]  = f2bf(fast_tanh(e1[j] + d1[j]));
#pragma unroll
            for (int j = 0; j < 4; ++j) v[8 + j]  = f2bf(fast_tanh(e2[j] + d2[j]));
#pragma unroll
            for (int j = 0; j < 4; ++j) v[12 + j] = f2bf(fast_tanh(e3[j] + d3[j]));
            *(int4v*)((char*)&As[nxt][0] + awb0) = *(const int4v*)&v[0];
            *(int4v*)((char*)&As[nxt][0] + awb1) = *(const int4v*)&v[8];
        }
        // 5) drain + barrier (loads had the whole iteration to complete)
        if (more) {
            asm volatile("s_waitcnt vmcnt(0) lgkmcnt(0)" ::: "memory");
            __builtin_amdgcn_s_barrier();
        }
    }

    // ---- epilogue: + b2, store fp32 ----
#pragma unroll
    for (int nf = 0; nf < 8; ++nf) {
        int n = n0 + wn * 128 + nf * 16 + l15;
        if (n < V_) {
            float bv = b2[n];
#pragma unroll
            for (int mf = 0; mf < 4; ++mf) {
#pragma unroll
                for (int j = 0; j < 4; ++j) {
                    int m = m0 + wm * 64 + mf * 16 + ksel * 4 + j;
                    if (m < M_TOT)
                        out[(long)m * V_ + n] = acc[mf][nf][j] + bv;
                }
            }
        }
    }
}

extern "C" void kernel_launch(void* const* d_in, const int* in_sizes, int n_in,
                              void* d_out, int out_size, void* d_ws, size_t ws_size,
                              hipStream_t stream) {
    const float* enc = (const float*)d_in[0];
    const float* dec = (const float*)d_in[1];
    const float* W1  = (const float*)d_in[2];
    const float* b1  = (const float*)d_in[3];
    const float* W2  = (const float*)d_in[4];
    const float* b2  = (const float*)d_in[5];
    float* out = (float*)d_out;

    char* ws = (char*)d_ws;
    size_t off = 0;
    short* W1t  = (short*)(ws + off); off += (size_t)1024 * WK * 2;
    short* W2t  = (short*)(ws + off); off += (size_t)1024 * WK * 2;
    float* encP = (float*)(ws + off); off += (size_t)1200 * PK * 4;
    float* decP = (float*)(ws + off);

    transpose_cvt<<<dim3(16, 16), 256, 0, stream>>>(W1, W1t, 1024, 1024, WK);
    transpose_cvt<<<dim3(16, 16), 256, 0, stream>>>(W2, W2t, 1024, 1000, WK);

    proj_gemm<<<dim3(19, 16), 256, 0, stream>>>(enc, 1200, 0,   W1t, nullptr, encP);
    proj_gemm<<<dim3(4, 16),  256, 0, stream>>>(dec, 240,  512, W1t, b1,      decP);

    joint_gemm<<<dim3((M_TOT + BM - 1) / BM, 1024 / BN), 256, 0, stream>>>(
        encP, decP, W2t, b2, out);
}